// Round 1
// baseline (378.812 us; speedup 1.0000x reference)
//
#include <hip/hip_runtime.h>

#define BB 64
#define TT 512
#define HH 1024
#define CC 21
#define NROWS (BB*TT)   // 32768

// ---------------------------------------------------------------------------
// Kernel 1: emissions = hs @ W + b   (fp32, memory-bound on hs: 128 MB)
// grid 512 blocks x 256 threads; 64 rows/block; wave w handles k%64 slice
// [16w,16w+16); LDS tile 64x64 padded stride 65 (<=2-way banks, free).
// W read with wave-uniform addresses -> scalar loads (SMEM pipe).
// ---------------------------------------------------------------------------
__global__ __launch_bounds__(256) void emis_gemm(const float* __restrict__ hs,
                                                 const float* __restrict__ W,
                                                 const float* __restrict__ bias,
                                                 float* __restrict__ out) {
  __shared__ float lds[5376];          // 21.5 KB: tile (4160) U reduce scratch (5376)
  const int tid  = threadIdx.x;
  const int lane = tid & 63;
  const int row0 = blockIdx.x * 64;
  const int sub  = __builtin_amdgcn_readfirstlane(tid >> 6);  // wave id, uniform

  if (blockIdx.x == 0 && tid == 0) out[(size_t)NROWS * CC] = 0.f;  // zero loss slot

  float acc[CC];
#pragma unroll
  for (int c = 0; c < CC; ++c) acc[c] = 0.f;

  float4 buf[4];
  // prologue: load chunk 0 (k = 0..63) into regs
#pragma unroll
  for (int i = 0; i < 4; ++i) {
    int l4 = tid + i * 256;
    int r = l4 >> 4, c4 = l4 & 15;
    buf[i] = *reinterpret_cast<const float4*>(hs + (size_t)(row0 + r) * HH + c4 * 4);
  }
#pragma unroll
  for (int i = 0; i < 4; ++i) {
    int l4 = tid + i * 256;
    int r = l4 >> 4, c4 = l4 & 15;
    lds[r * 65 + c4 * 4 + 0] = buf[i].x;
    lds[r * 65 + c4 * 4 + 1] = buf[i].y;
    lds[r * 65 + c4 * 4 + 2] = buf[i].z;
    lds[r * 65 + c4 * 4 + 3] = buf[i].w;
  }
  __syncthreads();

  for (int chunk = 0; chunk < 16; ++chunk) {
    const int k0 = chunk * 64;
    if (chunk < 15) {                 // prefetch next chunk into regs
#pragma unroll
      for (int i = 0; i < 4; ++i) {
        int l4 = tid + i * 256;
        int r = l4 >> 4, c4 = l4 & 15;
        buf[i] = *reinterpret_cast<const float4*>(hs + (size_t)(row0 + r) * HH + (k0 + 64) + c4 * 4);
      }
    }
    const float* Wp = W + (size_t)(k0 + sub * 16) * CC;   // uniform -> s_load
#pragma unroll
    for (int kk = 0; kk < 16; ++kk) {
      float x = lds[lane * 65 + sub * 16 + kk];
#pragma unroll
      for (int c = 0; c < CC; ++c) acc[c] = fmaf(x, Wp[kk * CC + c], acc[c]);
    }
    __syncthreads();
    if (chunk < 15) {
#pragma unroll
      for (int i = 0; i < 4; ++i) {
        int l4 = tid + i * 256;
        int r = l4 >> 4, c4 = l4 & 15;
        lds[r * 65 + c4 * 4 + 0] = buf[i].x;
        lds[r * 65 + c4 * 4 + 1] = buf[i].y;
        lds[r * 65 + c4 * 4 + 2] = buf[i].z;
        lds[r * 65 + c4 * 4 + 3] = buf[i].w;
      }
      __syncthreads();
    }
  }

  // cross-wave k-reduction through LDS
  if (sub > 0) {
#pragma unroll
    for (int c = 0; c < CC; ++c) lds[(sub - 1) * 1344 + lane * CC + c] = acc[c];
  }
  __syncthreads();
  if (sub == 0) {
#pragma unroll
    for (int c = 0; c < CC; ++c) {
      float v = acc[c] + lds[lane * CC + c] + lds[1344 + lane * CC + c]
                        + lds[2688 + lane * CC + c] + bias[c];
      lds[4032 + lane * CC + c] = v;
    }
  }
  __syncthreads();
  // coalesced store of this block's 64x21 output slab
  for (int idx = tid; idx < 1344; idx += 256)
    out[(size_t)row0 * CC + idx] = lds[4032 + idx];
}

// ---------------------------------------------------------------------------
// Kernel 2: CRF NLL. grid 64 (one block per batch) x 128 threads.
// wave 0: alpha scan (lane j = class j, replicated alpha in SGPRs via
//         readlane; E=exp(trans) prefolded so no per-step max tree).
// wave 1: numerator + sequence length.
// ---------------------------------------------------------------------------
__global__ __launch_bounds__(128) void crf_kernel(const float* __restrict__ em,
                                                  const float* __restrict__ trans,
                                                  const float* __restrict__ startT,
                                                  const float* __restrict__ endT,
                                                  const int* __restrict__ att,
                                                  const int* __restrict__ labels,
                                                  float* __restrict__ loss) {
  const int b    = blockIdx.x;
  const int tid  = threadIdx.x;
  const int wave = tid >> 6;
  const int lane = tid & 63;
  __shared__ float sh_num;
  __shared__ int   sh_len;

  const float L2E = 1.4426950408889634f;
  const float LN2 = 0.6931471805599453f;

  if (wave == 1) {
    // len = sum(mask), mask = (att & labels!=-100) with t0 forced true
    int cnt = 0;
    for (int t = lane; t < TT; t += 64) {
      bool m = (t == 0) || ((att[b * TT + t] != 0) && (labels[b * TT + t] != -100));
      cnt += m ? 1 : 0;
    }
#pragma unroll
    for (int off = 32; off >= 1; off >>= 1) cnt += __shfl_down(cnt, off);
    cnt = __shfl(cnt, 0);

    float s = 0.f;
    for (int t = lane + 1; t < TT; t += 64) {
      bool m = (att[b * TT + t] != 0) && (labels[b * TT + t] != -100);
      if (m) {
        int tp = labels[b * TT + t - 1], tc = labels[b * TT + t];
        s += trans[tp * CC + tc] + em[((size_t)b * TT + t) * CC + tc];
      }
    }
#pragma unroll
    for (int off = 32; off >= 1; off >>= 1) s += __shfl_down(s, off);
    if (lane == 0) {
      int tag0 = labels[b * TT];
      int lastTag = labels[b * TT + cnt - 1];
      s += startT[tag0] + em[((size_t)b * TT) * CC + tag0] + endT[lastTag];
      sh_num = s;
      sh_len = cnt;
    }
  }

  const int j = lane < CC ? lane : CC - 1;
  float E[CC];
  float a = 0.f;
  if (wave == 0) {
#pragma unroll
    for (int i = 0; i < CC; ++i)
      E[i] = __builtin_amdgcn_exp2f(trans[i * CC + j] * L2E);   // exp(trans[i][j])
    a = startT[j] + em[((size_t)b * TT) * CC + j];
  }
  __syncthreads();

  if (wave == 0) {
    const int len = sh_len;
    float sa[CC];
#pragma unroll
    for (int i = 0; i < CC; ++i)
      sa[i] = __int_as_float(__builtin_amdgcn_readlane(__float_as_int(a), i));

    const float* emB = em + (size_t)b * TT * CC;
    float em_cur = emB[1 * CC + j];          // in-bounds even when len==1
    for (int t = 1; t < len; ++t) {
      float em_nxt = emB[(size_t)(t + 1 < len ? t + 1 : t) * CC + j];
      float a0 = sa[0];
      float p[CC];
#pragma unroll
      for (int i = 0; i < CC; ++i)
        p[i] = __builtin_amdgcn_exp2f((sa[i] - a0) * L2E);      // exp(a_i - a0)
      float c0 = 0.f, c1 = 0.f, c2 = 0.f;
#pragma unroll
      for (int i = 0; i < CC; i += 3) c0 = fmaf(p[i], E[i], c0);
#pragma unroll
      for (int i = 1; i < CC; i += 3) c1 = fmaf(p[i], E[i], c1);
#pragma unroll
      for (int i = 2; i < CC; i += 3) c2 = fmaf(p[i], E[i], c2);
      float s = (c0 + c1) + c2;
      float anew = a0 + em_cur + LN2 * __builtin_amdgcn_logf(s);
      a = anew;
#pragma unroll
      for (int i = 0; i < CC; ++i)
        sa[i] = __int_as_float(__builtin_amdgcn_readlane(__float_as_int(anew), i));
      em_cur = em_nxt;
    }

    // logZ = logsumexp_j(alpha_j + end_j)
    float v = (lane < CC) ? (a + endT[j]) : -3.0e38f;
    float m = v;
#pragma unroll
    for (int off = 32; off >= 1; off >>= 1) m = fmaxf(m, __shfl_xor(m, off));
    float pe = (lane < CC) ? __builtin_amdgcn_exp2f((v - m) * L2E) : 0.f;
#pragma unroll
    for (int off = 32; off >= 1; off >>= 1) pe += __shfl_xor(pe, off);
    if (lane == 0) {
      float logZ = m + LN2 * __builtin_amdgcn_logf(pe);
      atomicAdd(loss, -(sh_num - logZ) * (1.0f / 64.0f));
    }
  }
}

extern "C" void kernel_launch(void* const* d_in, const int* in_sizes, int n_in,
                              void* d_out, int out_size, void* d_ws, size_t ws_size,
                              hipStream_t stream) {
  const float* hs     = (const float*)d_in[0];
  const float* W      = (const float*)d_in[1];
  const float* bias   = (const float*)d_in[2];
  const float* trans  = (const float*)d_in[3];
  const float* startT = (const float*)d_in[4];
  const float* endT   = (const float*)d_in[5];
  const int*   att    = (const int*)d_in[6];
  const int*   labels = (const int*)d_in[7];
  float* out = (float*)d_out;

  emis_gemm<<<dim3(512), dim3(256), 0, stream>>>(hs, W, bias, out);
  crf_kernel<<<dim3(64), dim3(128), 0, stream>>>(out, trans, startT, endT, att,
                                                 labels, out + (size_t)NROWS * CC);
}

// Round 2
// 333.353 us; speedup vs baseline: 1.1364x; 1.1364x over previous
//
#include <hip/hip_runtime.h>

#define BB 64
#define TT 512
#define HH 1024
#define CC 21
#define NROWS (BB*TT)   // 32768

// ---------------------------------------------------------------------------
// Kernel 1: emissions = hs @ W + b   (fp32, memory-bound on hs: 128 MB)
// unchanged from R1 — isolating the CRF change this round.
// ---------------------------------------------------------------------------
__global__ __launch_bounds__(256) void emis_gemm(const float* __restrict__ hs,
                                                 const float* __restrict__ W,
                                                 const float* __restrict__ bias,
                                                 float* __restrict__ out) {
  __shared__ float lds[5376];
  const int tid  = threadIdx.x;
  const int lane = tid & 63;
  const int row0 = blockIdx.x * 64;
  const int sub  = __builtin_amdgcn_readfirstlane(tid >> 6);

  if (blockIdx.x == 0 && tid == 0) out[(size_t)NROWS * CC] = 0.f;  // zero loss slot

  float acc[CC];
#pragma unroll
  for (int c = 0; c < CC; ++c) acc[c] = 0.f;

  float4 buf[4];
#pragma unroll
  for (int i = 0; i < 4; ++i) {
    int l4 = tid + i * 256;
    int r = l4 >> 4, c4 = l4 & 15;
    buf[i] = *reinterpret_cast<const float4*>(hs + (size_t)(row0 + r) * HH + c4 * 4);
  }
#pragma unroll
  for (int i = 0; i < 4; ++i) {
    int l4 = tid + i * 256;
    int r = l4 >> 4, c4 = l4 & 15;
    lds[r * 65 + c4 * 4 + 0] = buf[i].x;
    lds[r * 65 + c4 * 4 + 1] = buf[i].y;
    lds[r * 65 + c4 * 4 + 2] = buf[i].z;
    lds[r * 65 + c4 * 4 + 3] = buf[i].w;
  }
  __syncthreads();

  for (int chunk = 0; chunk < 16; ++chunk) {
    const int k0 = chunk * 64;
    if (chunk < 15) {
#pragma unroll
      for (int i = 0; i < 4; ++i) {
        int l4 = tid + i * 256;
        int r = l4 >> 4, c4 = l4 & 15;
        buf[i] = *reinterpret_cast<const float4*>(hs + (size_t)(row0 + r) * HH + (k0 + 64) + c4 * 4);
      }
    }
    const float* Wp = W + (size_t)(k0 + sub * 16) * CC;   // uniform -> s_load
#pragma unroll
    for (int kk = 0; kk < 16; ++kk) {
      float x = lds[lane * 65 + sub * 16 + kk];
#pragma unroll
      for (int c = 0; c < CC; ++c) acc[c] = fmaf(x, Wp[kk * CC + c], acc[c]);
    }
    __syncthreads();
    if (chunk < 15) {
#pragma unroll
      for (int i = 0; i < 4; ++i) {
        int l4 = tid + i * 256;
        int r = l4 >> 4, c4 = l4 & 15;
        lds[r * 65 + c4 * 4 + 0] = buf[i].x;
        lds[r * 65 + c4 * 4 + 1] = buf[i].y;
        lds[r * 65 + c4 * 4 + 2] = buf[i].z;
        lds[r * 65 + c4 * 4 + 3] = buf[i].w;
      }
      __syncthreads();
    }
  }

  if (sub > 0) {
#pragma unroll
    for (int c = 0; c < CC; ++c) lds[(sub - 1) * 1344 + lane * CC + c] = acc[c];
  }
  __syncthreads();
  if (sub == 0) {
#pragma unroll
    for (int c = 0; c < CC; ++c) {
      float v = acc[c] + lds[lane * CC + c] + lds[1344 + lane * CC + c]
                        + lds[2688 + lane * CC + c] + bias[c];
      lds[4032 + lane * CC + c] = v;
    }
  }
  __syncthreads();
  for (int idx = tid; idx < 1344; idx += 256)
    out[(size_t)row0 * CC + idx] = lds[4032 + idx];
}

// ---------------------------------------------------------------------------
// Kernel 2: CRF NLL — prob-space scan with power-of-2 renormalization.
// beta_j = exp(alpha_j - k*ln2); step: beta' = exp(em_t) * (E^T beta),
// E = exp(trans) precomputed. NO per-step transcendental on the critical
// path: exp(em) prefetched depth-3; renorm via exponent bit extraction
// (SALU); k accumulated as int, folded into logZ once.
// ---------------------------------------------------------------------------
__global__ __launch_bounds__(128) void crf_kernel(const float* __restrict__ em,
                                                  const float* __restrict__ trans,
                                                  const float* __restrict__ startT,
                                                  const float* __restrict__ endT,
                                                  const int* __restrict__ att,
                                                  const int* __restrict__ labels,
                                                  float* __restrict__ loss) {
  const int b    = blockIdx.x;
  const int tid  = threadIdx.x;
  const int wave = tid >> 6;
  const int lane = tid & 63;
  __shared__ float sh_num;
  __shared__ int   sh_len;

  const float L2E = 1.4426950408889634f;
  const float LN2 = 0.6931471805599453f;

  if (wave == 1) {
    // len = sum(mask); mask is a prefix here (labels never -100), t0 forced
    int cnt = 0;
    for (int t = lane; t < TT; t += 64) {
      bool m = (t == 0) || ((att[b * TT + t] != 0) && (labels[b * TT + t] != -100));
      cnt += m ? 1 : 0;
    }
#pragma unroll
    for (int off = 32; off >= 1; off >>= 1) cnt += __shfl_down(cnt, off);
    cnt = __shfl(cnt, 0);

    float s = 0.f;
    for (int t = lane + 1; t < TT; t += 64) {
      bool m = (att[b * TT + t] != 0) && (labels[b * TT + t] != -100);
      if (m) {
        int tp = labels[b * TT + t - 1], tc = labels[b * TT + t];
        s += trans[tp * CC + tc] + em[((size_t)b * TT + t) * CC + tc];
      }
    }
#pragma unroll
    for (int off = 32; off >= 1; off >>= 1) s += __shfl_down(s, off);
    if (lane == 0) {
      int tag0 = labels[b * TT];
      int lastTag = labels[b * TT + cnt - 1];
      s += startT[tag0] + em[((size_t)b * TT) * CC + tag0] + endT[lastTag];
      sh_num = s;
      sh_len = cnt;
    }
  }

  const int j = lane < CC ? lane : CC - 1;
  float E[CC];
  float beta = 0.f, endE = 0.f;
  if (wave == 0) {
#pragma unroll
    for (int i = 0; i < CC; ++i)
      E[i] = __builtin_amdgcn_exp2f(trans[i * CC + j] * L2E);   // exp(trans[i][j])
    beta = __builtin_amdgcn_exp2f((startT[j] + em[((size_t)b * TT) * CC + j]) * L2E);
    endE = __builtin_amdgcn_exp2f(endT[j] * L2E);
  }
  __syncthreads();

  if (wave == 0) {
    const int len = sh_len;
    int ksum = 0;

    // broadcast beta to SGPRs
    float sb[CC];
#pragma unroll
    for (int i = 0; i < CC; ++i)
      sb[i] = __int_as_float(__builtin_amdgcn_readlane(__float_as_int(beta), i));

    const float* emB = em + (size_t)b * TT * CC;
    // depth-3 raw-em prefetch (clamped indices; values unused past len-1)
    auto clampi = [&](int t) { return t < len ? t : (len - 1); };
    float r0 = emB[(size_t)clampi(1) * CC + j];
    float r1 = emB[(size_t)clampi(2) * CC + j];
    float r2 = emB[(size_t)clampi(3) * CC + j];

    for (int t = 1; t < len; ++t) {
      float rn = emB[(size_t)clampi(t + 3) * CC + j];     // load for t+3
      float pm = __builtin_amdgcn_exp2f(r0 * L2E);        // exp(em_t), off chain
      // matvec: nxt_j = sum_i sb[i] * E[i][j]
      float c0 = 0.f, c1 = 0.f, c2 = 0.f;
#pragma unroll
      for (int i = 0; i < CC; i += 3) c0 = fmaf(sb[i], E[i], c0);
#pragma unroll
      for (int i = 1; i < CC; i += 3) c1 = fmaf(sb[i], E[i], c1);
#pragma unroll
      for (int i = 2; i < CC; i += 3) c2 = fmaf(sb[i], E[i], c2);
      float nxt = ((c0 + c1) + c2) * pm;
      // power-of-2 renorm keyed on lane 0's exponent (SALU bit ops, no log)
      int bits0 = __builtin_amdgcn_readlane(__float_as_int(nxt), 0);
      int e = ((bits0 >> 23) & 255) - 127;
      ksum += e;
      float scale = __int_as_float((127 - e) << 23);
      beta = nxt * scale;
      // re-broadcast for next step
#pragma unroll
      for (int i = 0; i < CC; ++i)
        sb[i] = __int_as_float(__builtin_amdgcn_readlane(__float_as_int(beta), i));
      r0 = r1; r1 = r2; r2 = rn;
    }

    // logZ = ksum*ln2 + ln( sum_j beta_j * exp(end_j) )
    float v = (lane < CC) ? beta * endE : 0.f;
#pragma unroll
    for (int off = 32; off >= 1; off >>= 1) v += __shfl_xor(v, off);
    if (lane == 0) {
      float logZ = (float)ksum * LN2 + LN2 * __builtin_amdgcn_logf(v);
      atomicAdd(loss, -(sh_num - logZ) * (1.0f / 64.0f));
    }
  }
}

extern "C" void kernel_launch(void* const* d_in, const int* in_sizes, int n_in,
                              void* d_out, int out_size, void* d_ws, size_t ws_size,
                              hipStream_t stream) {
  const float* hs     = (const float*)d_in[0];
  const float* W      = (const float*)d_in[1];
  const float* bias   = (const float*)d_in[2];
  const float* trans  = (const float*)d_in[3];
  const float* startT = (const float*)d_in[4];
  const float* endT   = (const float*)d_in[5];
  const int*   att    = (const int*)d_in[6];
  const int*   labels = (const int*)d_in[7];
  float* out = (float*)d_out;

  emis_gemm<<<dim3(512), dim3(256), 0, stream>>>(hs, W, bias, out);
  crf_kernel<<<dim3(64), dim3(128), 0, stream>>>(out, trans, startT, endT, att,
                                                 labels, out + (size_t)NROWS * CC);
}

// Round 3
// 296.671 us; speedup vs baseline: 1.2769x; 1.1236x over previous
//
#include <hip/hip_runtime.h>

#define BB 64
#define TT 512
#define HH 1024
#define CC 21
#define NROWS (BB*TT)   // 32768

// ---------------------------------------------------------------------------
// Kernel 1: emissions = hs @ W + b.
// 512 blocks x 512 threads (8 waves): 64 rows/block, wave w owns k-slice
// [8w,8w+8) per 64-chunk (lane = row). Double-buffered LDS tile (stride 65:
// 2-way banks = free), 1 barrier/chunk. W via wave-uniform s_loads.
// 16 waves/CU (2 blocks x 8 waves), LDS 71 KB/block.
// ---------------------------------------------------------------------------
__global__ __launch_bounds__(512) void emis_gemm(const float* __restrict__ hs,
                                                 const float* __restrict__ W,
                                                 const float* __restrict__ bias,
                                                 float* __restrict__ out) {
  __shared__ float lds[17728];   // 2*4160 tile bufs + 7*1344 reduce scratch
  const int tid  = threadIdx.x;
  const int lane = tid & 63;
  const int w    = __builtin_amdgcn_readfirstlane(tid >> 6);
  const int row0 = blockIdx.x * 64;

  if (blockIdx.x == 0 && tid == 0) out[(size_t)NROWS * CC] = 0.f;  // loss slot

  float acc[CC];
#pragma unroll
  for (int c = 0; c < CC; ++c) acc[c] = 0.f;

  const int r_  = (tid) >> 4,        c4_  = tid & 15;        // element 0
  const int r2_ = (tid + 512) >> 4;                          // element 1 (same c4)

  float4 buf0, buf1;
  buf0 = *reinterpret_cast<const float4*>(hs + (size_t)(row0 + r_ ) * HH + c4_ * 4);
  buf1 = *reinterpret_cast<const float4*>(hs + (size_t)(row0 + r2_) * HH + c4_ * 4);
  {
    float* t0 = &lds[r_  * 65 + c4_ * 4];
    float* t1 = &lds[r2_ * 65 + c4_ * 4];
    t0[0] = buf0.x; t0[1] = buf0.y; t0[2] = buf0.z; t0[3] = buf0.w;
    t1[0] = buf1.x; t1[1] = buf1.y; t1[2] = buf1.z; t1[3] = buf1.w;
  }
  __syncthreads();

  for (int chunk = 0; chunk < 16; ++chunk) {
    const int cur = (chunk & 1) * 4160;
    const int nxt = ((chunk + 1) & 1) * 4160;
    if (chunk < 15) {   // prefetch next chunk into regs
      const int k0n = (chunk + 1) * 64;
      buf0 = *reinterpret_cast<const float4*>(hs + (size_t)(row0 + r_ ) * HH + k0n + c4_ * 4);
      buf1 = *reinterpret_cast<const float4*>(hs + (size_t)(row0 + r2_) * HH + k0n + c4_ * 4);
    }
    const float* Wp = W + (size_t)(chunk * 64 + w * 8) * CC;   // uniform -> s_load
#pragma unroll
    for (int kk = 0; kk < 8; ++kk) {
      float x = lds[cur + lane * 65 + w * 8 + kk];
#pragma unroll
      for (int c = 0; c < CC; ++c) acc[c] = fmaf(x, Wp[kk * CC + c], acc[c]);
    }
    if (chunk < 15) {
      float* t0 = &lds[nxt + r_  * 65 + c4_ * 4];
      float* t1 = &lds[nxt + r2_ * 65 + c4_ * 4];
      t0[0] = buf0.x; t0[1] = buf0.y; t0[2] = buf0.z; t0[3] = buf0.w;
      t1[0] = buf1.x; t1[1] = buf1.y; t1[2] = buf1.z; t1[3] = buf1.w;
    }
    __syncthreads();
  }

  // cross-wave k-reduction: waves 1..7 dump, wave 0 combines
  if (w > 0) {
#pragma unroll
    for (int c = 0; c < CC; ++c)
      lds[8320 + (w - 1) * 1344 + lane * CC + c] = acc[c];
  }
  __syncthreads();
  if (w == 0) {
#pragma unroll
    for (int c = 0; c < CC; ++c) {
      float v = acc[c] + bias[c];
#pragma unroll
      for (int q = 0; q < 7; ++q) v += lds[8320 + q * 1344 + lane * CC + c];
      lds[lane * CC + c] = v;
    }
  }
  __syncthreads();
  for (int idx = tid; idx < 1344; idx += 512)
    out[(size_t)row0 * CC + idx] = lds[idx];
}

// ---------------------------------------------------------------------------
// Kernel 2: CRF NLL — prob-space scan, lagged scalar renorm.
// beta'_j = pm_j * sum_i beta_i * E[i][j], E = exp(trans) precomputed.
// Renorm scale derived from sb[0] (SGPR) via SALU — OFF the VALU chain.
// Unroll-8 with depth-8 em prefetch (>= HBM latency lookahead).
// ---------------------------------------------------------------------------
__global__ __launch_bounds__(128) void crf_kernel(const float* __restrict__ em,
                                                  const float* __restrict__ trans,
                                                  const float* __restrict__ startT,
                                                  const float* __restrict__ endT,
                                                  const int* __restrict__ att,
                                                  const int* __restrict__ labels,
                                                  float* __restrict__ loss) {
  const int b    = blockIdx.x;
  const int tid  = threadIdx.x;
  const int wave = tid >> 6;
  const int lane = tid & 63;
  __shared__ float sh_num;
  __shared__ int   sh_len;

  const float L2E = 1.4426950408889634f;
  const float LN2 = 0.6931471805599453f;

  if (wave == 1) {
    int cnt = 0;
    for (int t = lane; t < TT; t += 64) {
      bool m = (t == 0) || ((att[b * TT + t] != 0) && (labels[b * TT + t] != -100));
      cnt += m ? 1 : 0;
    }
#pragma unroll
    for (int off = 32; off >= 1; off >>= 1) cnt += __shfl_down(cnt, off);
    cnt = __shfl(cnt, 0);

    float s = 0.f;
    for (int t = lane + 1; t < TT; t += 64) {
      bool m = (att[b * TT + t] != 0) && (labels[b * TT + t] != -100);
      if (m) {
        int tp = labels[b * TT + t - 1], tc = labels[b * TT + t];
        s += trans[tp * CC + tc] + em[((size_t)b * TT + t) * CC + tc];
      }
    }
#pragma unroll
    for (int off = 32; off >= 1; off >>= 1) s += __shfl_down(s, off);
    if (lane == 0) {
      int tag0 = labels[b * TT];
      int lastTag = labels[b * TT + cnt - 1];
      s += startT[tag0] + em[((size_t)b * TT) * CC + tag0] + endT[lastTag];
      sh_num = s;
      sh_len = cnt;
    }
  }

  const int j = lane < CC ? lane : CC - 1;
  float E[CC];
  float beta = 0.f, endE = 0.f;
  if (wave == 0) {
#pragma unroll
    for (int i = 0; i < CC; ++i)
      E[i] = __builtin_amdgcn_exp2f(trans[i * CC + j] * L2E);
    beta = __builtin_amdgcn_exp2f((startT[j] + em[((size_t)b * TT) * CC + j]) * L2E);
    endE = __builtin_amdgcn_exp2f(endT[j] * L2E);
  }
  __syncthreads();

  if (wave == 0) {
    const int len = sh_len;
    int ksum = 0;

    float sb[CC];
#pragma unroll
    for (int i = 0; i < CC; ++i)
      sb[i] = __int_as_float(__builtin_amdgcn_readlane(__float_as_int(beta), i));

    const float* emB = em + (size_t)b * TT * CC;

    // one scan step for time index `t` with raw emission value em_v.
    // scale comes from sb[0]'s exponent: SALU-only, parallel to FMA tree.
    auto step = [&](float em_v) {
      float pm = __builtin_amdgcn_exp2f(em_v * L2E);
      int ef = (__float_as_int(sb[0]) >> 23) & 255;
      ksum += ef - 127;
      float pms = pm * __int_as_float((254 - ef) << 23);
      float c0 = 0.f, c1 = 0.f, c2 = 0.f;
#pragma unroll
      for (int i = 0; i < CC; i += 3) c0 = fmaf(sb[i], E[i], c0);
#pragma unroll
      for (int i = 1; i < CC; i += 3) c1 = fmaf(sb[i], E[i], c1);
#pragma unroll
      for (int i = 2; i < CC; i += 3) c2 = fmaf(sb[i], E[i], c2);
      beta = ((c0 + c1) + c2) * pms;
#pragma unroll
      for (int i = 0; i < CC; ++i)
        sb[i] = __int_as_float(__builtin_amdgcn_readlane(__float_as_int(beta), i));
    };

    // depth-8 prefetch window
    float r[8];
#pragma unroll
    for (int u = 0; u < 8; ++u) {
      int tt = 1 + u; if (tt > len - 1) tt = len - 1;
      r[u] = emB[(size_t)tt * CC + j];
    }

    int t = 1;
    for (; t + 8 <= len; t += 8) {
#pragma unroll
      for (int u = 0; u < 8; ++u) {
        int tp = t + u + 8; if (tp > len - 1) tp = len - 1;
        float rn = emB[(size_t)tp * CC + j];
        step(r[u]);
        r[u] = rn;
      }
    }
    for (; t < len; ++t) {
      // remaining values are in r[0..]; after the unrolled loop, r[u] holds
      // em for time (t+u) by construction of the clamped prefetch
      step(r[0]);
#pragma unroll
      for (int u = 0; u < 7; ++u) r[u] = r[u + 1];
    }

    float v = (lane < CC) ? beta * endE : 0.f;
#pragma unroll
    for (int off = 32; off >= 1; off >>= 1) v += __shfl_xor(v, off);
    if (lane == 0) {
      float logZ = (float)ksum * LN2 + LN2 * __builtin_amdgcn_logf(v);
      atomicAdd(loss, -(sh_num - logZ) * (1.0f / 64.0f));
    }
  }
}

extern "C" void kernel_launch(void* const* d_in, const int* in_sizes, int n_in,
                              void* d_out, int out_size, void* d_ws, size_t ws_size,
                              hipStream_t stream) {
  const float* hs     = (const float*)d_in[0];
  const float* W      = (const float*)d_in[1];
  const float* bias   = (const float*)d_in[2];
  const float* trans  = (const float*)d_in[3];
  const float* startT = (const float*)d_in[4];
  const float* endT   = (const float*)d_in[5];
  const int*   att    = (const int*)d_in[6];
  const int*   labels = (const int*)d_in[7];
  float* out = (float*)d_out;

  emis_gemm<<<dim3(512), dim3(512), 0, stream>>>(hs, W, bias, out);
  crf_kernel<<<dim3(64), dim3(128), 0, stream>>>(out, trans, startT, endT, att,
                                                 labels, out + (size_t)NROWS * CC);
}

// Round 4
// 286.067 us; speedup vs baseline: 1.3242x; 1.0371x over previous
//
#include <hip/hip_runtime.h>

#define BB 64
#define TT 512
#define HH 1024
#define CC 21
#define NROWS (BB*TT)   // 32768
#define WPAD 24         // W row padded 21 -> 24 floats (16B-aligned float4 reads)
#define TSTR 65         // tile stride: 2-way bank alias only (free)
#define TSZ  (64*TSTR)  // 4160 floats per tile buffer

// ---------------------------------------------------------------------------
// Kernel 1: emissions = hs @ W + b.
// 512 blocks x 512 threads (8 waves); 64 rows/block; wave w owns k-slice
// [8w,8w+8) of each 64-wide chunk (lane = row).
// W is staged ONCE into LDS (padded rows of 24) and read per-kk as six
// uniform ds_read_b128 broadcasts -> NO scalar-memory traffic in the K-loop
// (R3's bottleneck: per-chunk W s_loads thrashed K$ and forced lgkmcnt(0)
// drains). All K-loop memory is DS (in-order) + the double-buffered global
// tile prefetch. LDS 128.5 KB -> 1 block/CU, 2 block-rounds over 256 CUs.
// ---------------------------------------------------------------------------
__global__ __launch_bounds__(512) void emis_gemm(const float* __restrict__ hs,
                                                 const float* __restrict__ W,
                                                 const float* __restrict__ bias,
                                                 float* __restrict__ out) {
  __shared__ float lds[32896];         // [0,24576): W padded; [24576,32896): 2 tile bufs
  float* Wl   = lds;
  float* tile = lds + 24576;
  const int tid  = threadIdx.x;
  const int lane = tid & 63;
  const int w    = __builtin_amdgcn_readfirstlane(tid >> 6);
  const int row0 = blockIdx.x * 64;

  if (blockIdx.x == 0 && tid == 0) out[(size_t)NROWS * CC] = 0.f;  // loss slot

  // ---- stage W -> LDS (21504 = 512*42 elements, coalesced) ----
  for (int i = 0; i < 42; ++i) {
    int idx = tid + i * 512;
    int k = idx / 21;                  // constant div -> magic multiply
    int c = idx - k * 21;
    Wl[k * WPAD + c] = W[idx];
  }

  float acc[CC];
#pragma unroll
  for (int c = 0; c < CC; ++c) acc[c] = 0.f;

  const int r_  = tid >> 4, c4_ = tid & 15;
  const int r2_ = (tid + 512) >> 4;    // rows 32..63, same c4

  float4 buf0 = *reinterpret_cast<const float4*>(hs + (size_t)(row0 + r_ ) * HH + c4_ * 4);
  float4 buf1 = *reinterpret_cast<const float4*>(hs + (size_t)(row0 + r2_) * HH + c4_ * 4);
  {
    float* t0 = &tile[r_  * TSTR + c4_ * 4];
    float* t1 = &tile[r2_ * TSTR + c4_ * 4];
    t0[0] = buf0.x; t0[1] = buf0.y; t0[2] = buf0.z; t0[3] = buf0.w;
    t1[0] = buf1.x; t1[1] = buf1.y; t1[2] = buf1.z; t1[3] = buf1.w;
  }
  __syncthreads();

  for (int chunk = 0; chunk < 16; ++chunk) {
    float* cur = tile + (chunk & 1) * TSZ;
    float* nxt = tile + ((chunk + 1) & 1) * TSZ;
    if (chunk < 15) {                  // prefetch next tile chunk into regs
      const int k0n = (chunk + 1) * 64;
      buf0 = *reinterpret_cast<const float4*>(hs + (size_t)(row0 + r_ ) * HH + k0n + c4_ * 4);
      buf1 = *reinterpret_cast<const float4*>(hs + (size_t)(row0 + r2_) * HH + k0n + c4_ * 4);
    }
    const float* wl = Wl + (chunk * 64 + w * 8) * WPAD;
#pragma unroll
    for (int kk = 0; kk < 8; ++kk) {
      float x = cur[lane * TSTR + w * 8 + kk];
      const float4* wr = reinterpret_cast<const float4*>(wl + kk * WPAD);
      float4 w0 = wr[0], w1 = wr[1], w2 = wr[2], w3 = wr[3], w4 = wr[4], w5 = wr[5];
      acc[ 0] = fmaf(x, w0.x, acc[ 0]);
      acc[ 1] = fmaf(x, w0.y, acc[ 1]);
      acc[ 2] = fmaf(x, w0.z, acc[ 2]);
      acc[ 3] = fmaf(x, w0.w, acc[ 3]);
      acc[ 4] = fmaf(x, w1.x, acc[ 4]);
      acc[ 5] = fmaf(x, w1.y, acc[ 5]);
      acc[ 6] = fmaf(x, w1.z, acc[ 6]);
      acc[ 7] = fmaf(x, w1.w, acc[ 7]);
      acc[ 8] = fmaf(x, w2.x, acc[ 8]);
      acc[ 9] = fmaf(x, w2.y, acc[ 9]);
      acc[10] = fmaf(x, w2.z, acc[10]);
      acc[11] = fmaf(x, w2.w, acc[11]);
      acc[12] = fmaf(x, w3.x, acc[12]);
      acc[13] = fmaf(x, w3.y, acc[13]);
      acc[14] = fmaf(x, w3.z, acc[14]);
      acc[15] = fmaf(x, w3.w, acc[15]);
      acc[16] = fmaf(x, w4.x, acc[16]);
      acc[17] = fmaf(x, w4.y, acc[17]);
      acc[18] = fmaf(x, w4.z, acc[18]);
      acc[19] = fmaf(x, w4.w, acc[19]);
      acc[20] = fmaf(x, w5.x, acc[20]);
    }
    if (chunk < 15) {
      float* t0 = &nxt[r_  * TSTR + c4_ * 4];
      float* t1 = &nxt[r2_ * TSTR + c4_ * 4];
      t0[0] = buf0.x; t0[1] = buf0.y; t0[2] = buf0.z; t0[3] = buf0.w;
      t1[0] = buf1.x; t1[1] = buf1.y; t1[2] = buf1.z; t1[3] = buf1.w;
    }
    __syncthreads();
  }

  // ---- cross-wave k-reduction (reuse W's LDS region as scratch) ----
  if (w > 0) {
#pragma unroll
    for (int c = 0; c < CC; ++c)
      Wl[(w - 1) * 1344 + lane * CC + c] = acc[c];
  }
  __syncthreads();
  if (w == 0) {
#pragma unroll
    for (int c = 0; c < CC; ++c) {
      float v = acc[c] + bias[c];
#pragma unroll
      for (int q = 0; q < 7; ++q) v += Wl[q * 1344 + lane * CC + c];
      Wl[9408 + lane * CC + c] = v;
    }
  }
  __syncthreads();
  for (int idx = tid; idx < 1344; idx += 512)
    out[(size_t)row0 * CC + idx] = Wl[9408 + idx];
}

// ---------------------------------------------------------------------------
// Kernel 2: CRF NLL — unchanged from R3 (isolating the GEMM change).
// ---------------------------------------------------------------------------
__global__ __launch_bounds__(128) void crf_kernel(const float* __restrict__ em,
                                                  const float* __restrict__ trans,
                                                  const float* __restrict__ startT,
                                                  const float* __restrict__ endT,
                                                  const int* __restrict__ att,
                                                  const int* __restrict__ labels,
                                                  float* __restrict__ loss) {
  const int b    = blockIdx.x;
  const int tid  = threadIdx.x;
  const int wave = tid >> 6;
  const int lane = tid & 63;
  __shared__ float sh_num;
  __shared__ int   sh_len;

  const float L2E = 1.4426950408889634f;
  const float LN2 = 0.6931471805599453f;

  if (wave == 1) {
    int cnt = 0;
    for (int t = lane; t < TT; t += 64) {
      bool m = (t == 0) || ((att[b * TT + t] != 0) && (labels[b * TT + t] != -100));
      cnt += m ? 1 : 0;
    }
#pragma unroll
    for (int off = 32; off >= 1; off >>= 1) cnt += __shfl_down(cnt, off);
    cnt = __shfl(cnt, 0);

    float s = 0.f;
    for (int t = lane + 1; t < TT; t += 64) {
      bool m = (att[b * TT + t] != 0) && (labels[b * TT + t] != -100);
      if (m) {
        int tp = labels[b * TT + t - 1], tc = labels[b * TT + t];
        s += trans[tp * CC + tc] + em[((size_t)b * TT + t) * CC + tc];
      }
    }
#pragma unroll
    for (int off = 32; off >= 1; off >>= 1) s += __shfl_down(s, off);
    if (lane == 0) {
      int tag0 = labels[b * TT];
      int lastTag = labels[b * TT + cnt - 1];
      s += startT[tag0] + em[((size_t)b * TT) * CC + tag0] + endT[lastTag];
      sh_num = s;
      sh_len = cnt;
    }
  }

  const int j = lane < CC ? lane : CC - 1;
  float E[CC];
  float beta = 0.f, endE = 0.f;
  if (wave == 0) {
#pragma unroll
    for (int i = 0; i < CC; ++i)
      E[i] = __builtin_amdgcn_exp2f(trans[i * CC + j] * L2E);
    beta = __builtin_amdgcn_exp2f((startT[j] + em[((size_t)b * TT) * CC + j]) * L2E);
    endE = __builtin_amdgcn_exp2f(endT[j] * L2E);
  }
  __syncthreads();

  if (wave == 0) {
    const int len = sh_len;
    int ksum = 0;

    float sb[CC];
#pragma unroll
    for (int i = 0; i < CC; ++i)
      sb[i] = __int_as_float(__builtin_amdgcn_readlane(__float_as_int(beta), i));

    const float* emB = em + (size_t)b * TT * CC;

    auto step = [&](float em_v) {
      float pm = __builtin_amdgcn_exp2f(em_v * L2E);
      int ef = (__float_as_int(sb[0]) >> 23) & 255;
      ksum += ef - 127;
      float pms = pm * __int_as_float((254 - ef) << 23);
      float c0 = 0.f, c1 = 0.f, c2 = 0.f;
#pragma unroll
      for (int i = 0; i < CC; i += 3) c0 = fmaf(sb[i], E[i], c0);
#pragma unroll
      for (int i = 1; i < CC; i += 3) c1 = fmaf(sb[i], E[i], c1);
#pragma unroll
      for (int i = 2; i < CC; i += 3) c2 = fmaf(sb[i], E[i], c2);
      beta = ((c0 + c1) + c2) * pms;
#pragma unroll
      for (int i = 0; i < CC; ++i)
        sb[i] = __int_as_float(__builtin_amdgcn_readlane(__float_as_int(beta), i));
    };

    float r[8];
#pragma unroll
    for (int u = 0; u < 8; ++u) {
      int tt = 1 + u; if (tt > len - 1) tt = len - 1;
      r[u] = emB[(size_t)tt * CC + j];
    }

    int t = 1;
    for (; t + 8 <= len; t += 8) {
#pragma unroll
      for (int u = 0; u < 8; ++u) {
        int tp = t + u + 8; if (tp > len - 1) tp = len - 1;
        float rn = emB[(size_t)tp * CC + j];
        step(r[u]);
        r[u] = rn;
      }
    }
    for (; t < len; ++t) {
      step(r[0]);
#pragma unroll
      for (int u = 0; u < 7; ++u) r[u] = r[u + 1];
    }

    float v = (lane < CC) ? beta * endE : 0.f;
#pragma unroll
    for (int off = 32; off >= 1; off >>= 1) v += __shfl_xor(v, off);
    if (lane == 0) {
      float logZ = (float)ksum * LN2 + LN2 * __builtin_amdgcn_logf(v);
      atomicAdd(loss, -(sh_num - logZ) * (1.0f / 64.0f));
    }
  }
}

extern "C" void kernel_launch(void* const* d_in, const int* in_sizes, int n_in,
                              void* d_out, int out_size, void* d_ws, size_t ws_size,
                              hipStream_t stream) {
  const float* hs     = (const float*)d_in[0];
  const float* W      = (const float*)d_in[1];
  const float* bias   = (const float*)d_in[2];
  const float* trans  = (const float*)d_in[3];
  const float* startT = (const float*)d_in[4];
  const float* endT   = (const float*)d_in[5];
  const int*   att    = (const int*)d_in[6];
  const int*   labels = (const int*)d_in[7];
  float* out = (float*)d_out;

  emis_gemm<<<dim3(512), dim3(512), 0, stream>>>(hs, W, bias, out);
  crf_kernel<<<dim3(64), dim3(128), 0, stream>>>(out, trans, startT, endT, att,
                                                 labels, out + (size_t)NROWS * CC);
}